// Round 3
// baseline (1489.721 us; speedup 1.0000x reference)
//
#include <hip/hip_runtime.h>

// STN fused, one block per image, 256 threads.
// Round-3 changes vs round-2:
//  - only img / w1 / h1 / tiny activations in LDS (~18.9 KB -> 8 blocks/CU);
//    conv2 weights, fc1/fc2 weights, and all biases read direct from global (L1/L2-hot)
//  - output written directly (per-lane 12B contiguous = coalesced), staging gone
//  - stage-A transpose indexed by pixel (no integer div, 3.06 iters)
//  - __launch_bounds__(256,8) pins VGPR <= 64 for 32 waves/CU

__launch_bounds__(256, 8)
__global__ void stn_fused_kernel(
    const float* __restrict__ x,
    const float* __restrict__ w1, const float* __restrict__ b1,
    const float* __restrict__ w2, const float* __restrict__ b2,
    const float* __restrict__ fc1w, const float* __restrict__ fc1b,
    const float* __restrict__ fc2w, const float* __restrict__ fc2b,
    float* __restrict__ out)
{
    __shared__ __align__(16) float s_img[3 * 28 * 28];    // 2352, CHW
    __shared__ __align__(16) float s_w1[8 * 3 * 7 * 7];   // 1176
    __shared__ __align__(16) float s_h1[8 * 11 * 12];     // pooled1, rows padded to 12
    __shared__ float s_h2[90];
    __shared__ float s_fch[32];
    __shared__ float s_theta[6];

    const int t = threadIdx.x;
    const int n = blockIdx.x;
    const float* img = x + (size_t)n * 2352;

    // ---- Stage A: image HWC -> LDS CHW (pixel-indexed, no div), w1 -> LDS
    for (int p = t; p < 784; p += 256) {
        float v0 = img[3 * p + 0];
        float v1 = img[3 * p + 1];
        float v2 = img[3 * p + 2];
        s_img[p] = v0;
        s_img[784 + p] = v1;
        s_img[1568 + p] = v2;
    }
    for (int i = t; i < 1176; i += 256) s_w1[i] = w1[i];
    __syncthreads();

    // ---- Stage B: conv1 (3->8, 7x7) + 2x2 maxpool + relu -> s_h1 [8][11][12]
    // t = i*8 + o: wave holds 8 distinct rows (distinct bank-groups) x 8 bcast channels.
    if (t < 176) {
        const int i = t >> 3, o = t & 7;
        float acc[22];
        const float bias = b1[o];
        #pragma unroll
        for (int j = 0; j < 22; ++j) acc[j] = bias;
        for (int c = 0; c < 3; ++c) {
            #pragma unroll
            for (int kh = 0; kh < 7; ++kh) {
                const float* irow = &s_img[c * 784 + (i + kh) * 28];
                float im[28];
                #pragma unroll
                for (int q = 0; q < 7; ++q) {
                    float4 v = ((const float4*)irow)[q];
                    im[4 * q + 0] = v.x; im[4 * q + 1] = v.y;
                    im[4 * q + 2] = v.z; im[4 * q + 3] = v.w;
                }
                const float* wr = &s_w1[(o * 3 + c) * 49 + kh * 7];
                float wv[7];
                #pragma unroll
                for (int q = 0; q < 7; ++q) wv[q] = wr[q];
                #pragma unroll
                for (int kw = 0; kw < 7; ++kw) {
                    #pragma unroll
                    for (int j = 0; j < 22; ++j)
                        acc[j] += im[j + kw] * wv[kw];
                }
            }
        }
        // horizontal pair-max in regs
        float hm[11];
        #pragma unroll
        for (int j = 0; j < 11; ++j) hm[j] = fmaxf(acc[2 * j], acc[2 * j + 1]);
        // vertical pair-max via shfl: partner row i^1 is lane^8 (same wave)
        #pragma unroll
        for (int j = 0; j < 11; ++j) {
            float v = __shfl_xor(hm[j], 8);
            hm[j] = fmaxf(hm[j], v);
        }
        if ((i & 1) == 0) {
            float* row = &s_h1[(o * 11 + (i >> 1)) * 12];
            #pragma unroll
            for (int j = 0; j < 11; ++j) row[j] = fmaxf(hm[j], 0.0f);
        }
    }
    __syncthreads();

    // ---- Stage D: conv2 (8->10, 5x5) + 2x2 maxpool + relu -> s_h2[90]
    // t = o*6 + i; weights direct from global (8 KB, L1/L2-hot across all blocks).
    if (t < 60) {
        const int o = t / 6, i = t - 6 * (t / 6);
        float acc2[6];
        const float bias = b2[o];
        #pragma unroll
        for (int j = 0; j < 6; ++j) acc2[j] = bias;
        for (int c = 0; c < 8; ++c) {
            #pragma unroll
            for (int kh = 0; kh < 5; ++kh) {
                const float* hrow = &s_h1[(c * 11 + i + kh) * 12];
                float im2[12];
                #pragma unroll
                for (int q = 0; q < 3; ++q) {
                    float4 v = ((const float4*)hrow)[q];
                    im2[4 * q + 0] = v.x; im2[4 * q + 1] = v.y;
                    im2[4 * q + 2] = v.z; im2[4 * q + 3] = v.w;
                }
                const float* wr = &w2[(o * 8 + c) * 25 + kh * 5];
                float wv[5];
                #pragma unroll
                for (int q = 0; q < 5; ++q) wv[q] = wr[q];
                #pragma unroll
                for (int kw = 0; kw < 5; ++kw) {
                    #pragma unroll
                    for (int j = 0; j < 6; ++j)
                        acc2[j] += im2[j + kw] * wv[kw];
                }
            }
        }
        float hp[3];
        #pragma unroll
        for (int q = 0; q < 3; ++q) hp[q] = fmaxf(acc2[2 * q], acc2[2 * q + 1]);
        #pragma unroll
        for (int q = 0; q < 3; ++q) {
            float v = __shfl_xor(hp[q], 1);   // partner i^1 = lane^1
            hp[q] = fmaxf(hp[q], v);
        }
        if ((i & 1) == 0) {
            #pragma unroll
            for (int q = 0; q < 3; ++q)
                s_h2[o * 9 + (i >> 1) * 3 + q] = fmaxf(hp[q], 0.0f);
        }
    }
    __syncthreads();

    // ---- Stage F: fc1 (90->32) + relu; weights direct from global (11.5 KB, L2-hot)
    if (t < 32) {
        float acc = fc1b[t];
        const float* wr = &fc1w[t * 90];
        #pragma unroll 6
        for (int j = 0; j < 90; ++j) acc += s_h2[j] * wr[j];
        s_fch[t] = fmaxf(acc, 0.0f);
    }
    __syncthreads();

    // ---- Stage G: fc2 (32->6) -> theta; weights direct from global
    if (t < 6) {
        float acc = fc2b[t];
        const float* wr = &fc2w[t * 32];
        #pragma unroll
        for (int j = 0; j < 32; ++j) acc += s_fch[j] * wr[j];
        s_theta[t] = acc;
    }
    __syncthreads();

    const float t00 = s_theta[0], t01 = s_theta[1], t02 = s_theta[2];
    const float t10 = s_theta[3], t11 = s_theta[4], t12 = s_theta[5];

    // ---- Stage H: affine grid + bilinear sample -> direct coalesced store
    float* outp = out + (size_t)n * 2352;
    for (int p = t; p < 784; p += 256) {
        int h = p / 28, w = p - 28 * h;
        float xs = (2.0f * w + 1.0f) * (1.0f / 28.0f) - 1.0f;
        float ys = (2.0f * h + 1.0f) * (1.0f / 28.0f) - 1.0f;
        float gx = t00 * xs + t01 * ys + t02;
        float gy = t10 * xs + t11 * ys + t12;
        float ix = ((gx + 1.0f) * 28.0f - 1.0f) * 0.5f;
        float iy = ((gy + 1.0f) * 28.0f - 1.0f) * 0.5f;
        float x0f = floorf(ix), y0f = floorf(iy);
        float wx1 = ix - x0f, wx0 = 1.0f - wx1;
        float wy1 = iy - y0f, wy0 = 1.0f - wy1;
        int x0 = (int)x0f, y0 = (int)y0f;
        int x1 = x0 + 1, y1 = y0 + 1;
        float fx0 = (x0 >= 0 && x0 < 28) ? 1.0f : 0.0f;
        float fx1 = (x1 >= 0 && x1 < 28) ? 1.0f : 0.0f;
        float fy0 = (y0 >= 0 && y0 < 28) ? 1.0f : 0.0f;
        float fy1 = (y1 >= 0 && y1 < 28) ? 1.0f : 0.0f;
        float w00 = wx0 * wy0 * fx0 * fy0;
        float w10 = wx1 * wy0 * fx1 * fy0;
        float w01 = wx0 * wy1 * fx0 * fy1;
        float w11 = wx1 * wy1 * fx1 * fy1;
        int cx0 = min(max(x0, 0), 27), cx1 = min(max(x1, 0), 27);
        int cy0 = min(max(y0, 0), 27), cy1 = min(max(y1, 0), 27);
        int i00 = cy0 * 28 + cx0, i10 = cy0 * 28 + cx1;
        int i01 = cy1 * 28 + cx0, i11 = cy1 * 28 + cx1;
        float* o3 = outp + 3 * p;
        #pragma unroll
        for (int c = 0; c < 3; ++c) {
            const float* ic = &s_img[c * 784];
            float v = ic[i00] * w00 + ic[i10] * w10 + ic[i01] * w01 + ic[i11] * w11;
            o3[c] = v;
        }
    }
}

extern "C" void kernel_launch(void* const* d_in, const int* in_sizes, int n_in,
                              void* d_out, int out_size, void* d_ws, size_t ws_size,
                              hipStream_t stream) {
    const float* x     = (const float*)d_in[0];
    const float* w1    = (const float*)d_in[1];
    const float* b1    = (const float*)d_in[2];
    const float* w2    = (const float*)d_in[3];
    const float* b2    = (const float*)d_in[4];
    const float* fc1w  = (const float*)d_in[5];
    const float* fc1b  = (const float*)d_in[6];
    const float* fc2w  = (const float*)d_in[7];
    const float* fc2b  = (const float*)d_in[8];
    float* outp = (float*)d_out;

    const int n_img = 64 * 256;  // b*n
    stn_fused_kernel<<<dim3(n_img), dim3(256), 0, stream>>>(
        x, w1, b1, w2, b2, fc1w, fc1b, fc2w, fc2b, outp);
}

// Round 4
// 347.498 us; speedup vs baseline: 4.2870x; 4.2870x over previous
//
#include <hip/hip_runtime.h>

// STN fused, one block per image, 256 threads.
// Round-4 change vs round-3: __launch_bounds__(256,4) (NOT (256,8)).
// (256,8) forced a 32-VGPR target -> massive scratch spill (5 GB HBM traffic,
// 1490 us). Compiler lands at 64 VGPR under the 128 cap, and with 18.9 KB LDS
// the HW then schedules 8 blocks/CU on its own.

__launch_bounds__(256, 4)
__global__ void stn_fused_kernel(
    const float* __restrict__ x,
    const float* __restrict__ w1, const float* __restrict__ b1,
    const float* __restrict__ w2, const float* __restrict__ b2,
    const float* __restrict__ fc1w, const float* __restrict__ fc1b,
    const float* __restrict__ fc2w, const float* __restrict__ fc2b,
    float* __restrict__ out)
{
    __shared__ __align__(16) float s_img[3 * 28 * 28];    // 2352, CHW
    __shared__ __align__(16) float s_w1[8 * 3 * 7 * 7];   // 1176
    __shared__ __align__(16) float s_h1[8 * 11 * 12];     // pooled1, rows padded to 12
    __shared__ float s_h2[90];
    __shared__ float s_fch[32];
    __shared__ float s_theta[6];

    const int t = threadIdx.x;
    const int n = blockIdx.x;
    const float* img = x + (size_t)n * 2352;

    // ---- Stage A: image HWC -> LDS CHW (pixel-indexed, no div), w1 -> LDS
    for (int p = t; p < 784; p += 256) {
        float v0 = img[3 * p + 0];
        float v1 = img[3 * p + 1];
        float v2 = img[3 * p + 2];
        s_img[p] = v0;
        s_img[784 + p] = v1;
        s_img[1568 + p] = v2;
    }
    for (int i = t; i < 1176; i += 256) s_w1[i] = w1[i];
    __syncthreads();

    // ---- Stage B: conv1 (3->8, 7x7) + 2x2 maxpool + relu -> s_h1 [8][11][12]
    // t = i*8 + o: wave holds 8 distinct rows (distinct bank-groups) x 8 bcast channels.
    if (t < 176) {
        const int i = t >> 3, o = t & 7;
        float acc[22];
        const float bias = b1[o];
        #pragma unroll
        for (int j = 0; j < 22; ++j) acc[j] = bias;
        for (int c = 0; c < 3; ++c) {
            #pragma unroll
            for (int kh = 0; kh < 7; ++kh) {
                const float* irow = &s_img[c * 784 + (i + kh) * 28];
                float im[28];
                #pragma unroll
                for (int q = 0; q < 7; ++q) {
                    float4 v = ((const float4*)irow)[q];
                    im[4 * q + 0] = v.x; im[4 * q + 1] = v.y;
                    im[4 * q + 2] = v.z; im[4 * q + 3] = v.w;
                }
                const float* wr = &s_w1[(o * 3 + c) * 49 + kh * 7];
                float wv[7];
                #pragma unroll
                for (int q = 0; q < 7; ++q) wv[q] = wr[q];
                #pragma unroll
                for (int kw = 0; kw < 7; ++kw) {
                    #pragma unroll
                    for (int j = 0; j < 22; ++j)
                        acc[j] += im[j + kw] * wv[kw];
                }
            }
        }
        // horizontal pair-max in regs
        float hm[11];
        #pragma unroll
        for (int j = 0; j < 11; ++j) hm[j] = fmaxf(acc[2 * j], acc[2 * j + 1]);
        // vertical pair-max via shfl: partner row i^1 is lane^8 (same wave)
        #pragma unroll
        for (int j = 0; j < 11; ++j) {
            float v = __shfl_xor(hm[j], 8);
            hm[j] = fmaxf(hm[j], v);
        }
        if ((i & 1) == 0) {
            float* row = &s_h1[(o * 11 + (i >> 1)) * 12];
            #pragma unroll
            for (int j = 0; j < 11; ++j) row[j] = fmaxf(hm[j], 0.0f);
        }
    }
    __syncthreads();

    // ---- Stage D: conv2 (8->10, 5x5) + 2x2 maxpool + relu -> s_h2[90]
    // t = o*6 + i; weights direct from global (8 KB, L1/L2-hot across all blocks).
    if (t < 60) {
        const int o = t / 6, i = t - 6 * (t / 6);
        float acc2[6];
        const float bias = b2[o];
        #pragma unroll
        for (int j = 0; j < 6; ++j) acc2[j] = bias;
        for (int c = 0; c < 8; ++c) {
            #pragma unroll
            for (int kh = 0; kh < 5; ++kh) {
                const float* hrow = &s_h1[(c * 11 + i + kh) * 12];
                float im2[12];
                #pragma unroll
                for (int q = 0; q < 3; ++q) {
                    float4 v = ((const float4*)hrow)[q];
                    im2[4 * q + 0] = v.x; im2[4 * q + 1] = v.y;
                    im2[4 * q + 2] = v.z; im2[4 * q + 3] = v.w;
                }
                const float* wr = &w2[(o * 8 + c) * 25 + kh * 5];
                float wv[5];
                #pragma unroll
                for (int q = 0; q < 5; ++q) wv[q] = wr[q];
                #pragma unroll
                for (int kw = 0; kw < 5; ++kw) {
                    #pragma unroll
                    for (int j = 0; j < 6; ++j)
                        acc2[j] += im2[j + kw] * wv[kw];
                }
            }
        }
        float hp[3];
        #pragma unroll
        for (int q = 0; q < 3; ++q) hp[q] = fmaxf(acc2[2 * q], acc2[2 * q + 1]);
        #pragma unroll
        for (int q = 0; q < 3; ++q) {
            float v = __shfl_xor(hp[q], 1);   // partner i^1 = lane^1
            hp[q] = fmaxf(hp[q], v);
        }
        if ((i & 1) == 0) {
            #pragma unroll
            for (int q = 0; q < 3; ++q)
                s_h2[o * 9 + (i >> 1) * 3 + q] = fmaxf(hp[q], 0.0f);
        }
    }
    __syncthreads();

    // ---- Stage F: fc1 (90->32) + relu; weights direct from global (11.5 KB, L2-hot)
    if (t < 32) {
        float acc = fc1b[t];
        const float* wr = &fc1w[t * 90];
        #pragma unroll 6
        for (int j = 0; j < 90; ++j) acc += s_h2[j] * wr[j];
        s_fch[t] = fmaxf(acc, 0.0f);
    }
    __syncthreads();

    // ---- Stage G: fc2 (32->6) -> theta; weights direct from global
    if (t < 6) {
        float acc = fc2b[t];
        const float* wr = &fc2w[t * 32];
        #pragma unroll
        for (int j = 0; j < 32; ++j) acc += s_fch[j] * wr[j];
        s_theta[t] = acc;
    }
    __syncthreads();

    const float t00 = s_theta[0], t01 = s_theta[1], t02 = s_theta[2];
    const float t10 = s_theta[3], t11 = s_theta[4], t12 = s_theta[5];

    // ---- Stage H: affine grid + bilinear sample -> direct coalesced store
    float* outp = out + (size_t)n * 2352;
    for (int p = t; p < 784; p += 256) {
        int h = p / 28, w = p - 28 * h;
        float xs = (2.0f * w + 1.0f) * (1.0f / 28.0f) - 1.0f;
        float ys = (2.0f * h + 1.0f) * (1.0f / 28.0f) - 1.0f;
        float gx = t00 * xs + t01 * ys + t02;
        float gy = t10 * xs + t11 * ys + t12;
        float ix = ((gx + 1.0f) * 28.0f - 1.0f) * 0.5f;
        float iy = ((gy + 1.0f) * 28.0f - 1.0f) * 0.5f;
        float x0f = floorf(ix), y0f = floorf(iy);
        float wx1 = ix - x0f, wx0 = 1.0f - wx1;
        float wy1 = iy - y0f, wy0 = 1.0f - wy1;
        int x0 = (int)x0f, y0 = (int)y0f;
        int x1 = x0 + 1, y1 = y0 + 1;
        float fx0 = (x0 >= 0 && x0 < 28) ? 1.0f : 0.0f;
        float fx1 = (x1 >= 0 && x1 < 28) ? 1.0f : 0.0f;
        float fy0 = (y0 >= 0 && y0 < 28) ? 1.0f : 0.0f;
        float fy1 = (y1 >= 0 && y1 < 28) ? 1.0f : 0.0f;
        float w00 = wx0 * wy0 * fx0 * fy0;
        float w10 = wx1 * wy0 * fx1 * fy0;
        float w01 = wx0 * wy1 * fx0 * fy1;
        float w11 = wx1 * wy1 * fx1 * fy1;
        int cx0 = min(max(x0, 0), 27), cx1 = min(max(x1, 0), 27);
        int cy0 = min(max(y0, 0), 27), cy1 = min(max(y1, 0), 27);
        int i00 = cy0 * 28 + cx0, i10 = cy0 * 28 + cx1;
        int i01 = cy1 * 28 + cx0, i11 = cy1 * 28 + cx1;
        float* o3 = outp + 3 * p;
        #pragma unroll
        for (int c = 0; c < 3; ++c) {
            const float* ic = &s_img[c * 784];
            float v = ic[i00] * w00 + ic[i10] * w10 + ic[i01] * w01 + ic[i11] * w11;
            o3[c] = v;
        }
    }
}

extern "C" void kernel_launch(void* const* d_in, const int* in_sizes, int n_in,
                              void* d_out, int out_size, void* d_ws, size_t ws_size,
                              hipStream_t stream) {
    const float* x     = (const float*)d_in[0];
    const float* w1    = (const float*)d_in[1];
    const float* b1    = (const float*)d_in[2];
    const float* w2    = (const float*)d_in[3];
    const float* b2    = (const float*)d_in[4];
    const float* fc1w  = (const float*)d_in[5];
    const float* fc1b  = (const float*)d_in[6];
    const float* fc2w  = (const float*)d_in[7];
    const float* fc2b  = (const float*)d_in[8];
    float* outp = (float*)d_out;

    const int n_img = 64 * 256;  // b*n
    stn_fused_kernel<<<dim3(n_img), dim3(256), 0, stream>>>(
        x, w1, b1, w2, b2, fc1w, fc1b, fc2w, fc2b, outp);
}

// Round 5
// 338.694 us; speedup vs baseline: 4.3984x; 1.0260x over previous
//
#include <hip/hip_runtime.h>

// STN, round 5: two-kernel split.
// K1 = localization net -> theta (one block/image, 256 thr). Conv1 mapping
//     unchanged; conv2/fc1/fc2 wave-parallelized (shfl butterfly reductions)
//     to shorten the per-block serial tail.
// K2 = affine grid + bilinear sample (one block/image, no LDS, direct global
//     taps; x is L1/L3-hot). Memory-bound, removed from K1's latency path.

__launch_bounds__(256, 4)
__global__ void stn_loc_kernel(
    const float* __restrict__ x,
    const float* __restrict__ w1, const float* __restrict__ b1,
    const float* __restrict__ w2, const float* __restrict__ b2,
    const float* __restrict__ fc1w, const float* __restrict__ fc1b,
    const float* __restrict__ fc2w, const float* __restrict__ fc2b,
    float* __restrict__ theta_ws)
{
    __shared__ __align__(16) float s_img[3 * 28 * 28];    // 2352, CHW
    __shared__ __align__(16) float s_w1[8 * 3 * 7 * 7];   // 1176
    __shared__ __align__(16) float s_h1[8 * 11 * 12];     // pooled1, rows padded to 12
    __shared__ float s_h2[90];
    __shared__ float s_fch[32];

    const int t = threadIdx.x;
    const int n = blockIdx.x;
    const float* img = x + (size_t)n * 2352;

    // ---- Stage A: image HWC -> LDS CHW (pixel-indexed), w1 -> LDS
    for (int p = t; p < 784; p += 256) {
        float v0 = img[3 * p + 0];
        float v1 = img[3 * p + 1];
        float v2 = img[3 * p + 2];
        s_img[p] = v0;
        s_img[784 + p] = v1;
        s_img[1568 + p] = v2;
    }
    for (int i = t; i < 1176; i += 256) s_w1[i] = w1[i];
    __syncthreads();

    // ---- Stage B: conv1 (3->8, 7x7) + 2x2 maxpool + relu -> s_h1 [8][11][12]
    // t = i*8 + o: wave holds 8 distinct rows (distinct bank-groups) x 8 bcast channels.
    if (t < 176) {
        const int i = t >> 3, o = t & 7;
        float acc[22];
        const float bias = b1[o];
        #pragma unroll
        for (int j = 0; j < 22; ++j) acc[j] = bias;
        for (int c = 0; c < 3; ++c) {
            #pragma unroll
            for (int kh = 0; kh < 7; ++kh) {
                const float* irow = &s_img[c * 784 + (i + kh) * 28];
                float im[28];
                #pragma unroll
                for (int q = 0; q < 7; ++q) {
                    float4 v = ((const float4*)irow)[q];
                    im[4 * q + 0] = v.x; im[4 * q + 1] = v.y;
                    im[4 * q + 2] = v.z; im[4 * q + 3] = v.w;
                }
                const float* wr = &s_w1[(o * 3 + c) * 49 + kh * 7];
                float wv[7];
                #pragma unroll
                for (int q = 0; q < 7; ++q) wv[q] = wr[q];
                #pragma unroll
                for (int kw = 0; kw < 7; ++kw) {
                    #pragma unroll
                    for (int j = 0; j < 22; ++j)
                        acc[j] += im[j + kw] * wv[kw];
                }
            }
        }
        float hm[11];
        #pragma unroll
        for (int j = 0; j < 11; ++j) hm[j] = fmaxf(acc[2 * j], acc[2 * j + 1]);
        #pragma unroll
        for (int j = 0; j < 11; ++j) {
            float v = __shfl_xor(hm[j], 8);   // partner row i^1 = lane^8
            hm[j] = fmaxf(hm[j], v);
        }
        if ((i & 1) == 0) {
            float* row = &s_h1[(o * 11 + (i >> 1)) * 12];
            #pragma unroll
            for (int j = 0; j < 11; ++j) row[j] = fmaxf(hm[j], 0.0f);
        }
    }
    __syncthreads();

    // ---- Stage D: conv2 (8->10, 5x5) + 2x2 maxpool + relu -> s_h2[90]
    // 240 threads: t = (o*6+i)*4 + cg; cg in lane bits 0..1 splits the 8 input
    // channels 4-way (2 each); butterfly reduce shfl_xor 1,2; pool partner = xor 4.
    if (t < 240) {
        const int cg = t & 3;
        const int r = t >> 2;                 // 0..59
        const int o = r / 6, i = r - 6 * (r / 6);
        float acc2[6];
        #pragma unroll
        for (int j = 0; j < 6; ++j) acc2[j] = 0.0f;
        #pragma unroll
        for (int cc = 0; cc < 2; ++cc) {
            const int c = 2 * cg + cc;
            #pragma unroll
            for (int kh = 0; kh < 5; ++kh) {
                const float* hrow = &s_h1[(c * 11 + i + kh) * 12];
                float im2[12];
                #pragma unroll
                for (int q = 0; q < 3; ++q) {
                    float4 v = ((const float4*)hrow)[q];
                    im2[4 * q + 0] = v.x; im2[4 * q + 1] = v.y;
                    im2[4 * q + 2] = v.z; im2[4 * q + 3] = v.w;
                }
                const float* wr = &w2[(o * 8 + c) * 25 + kh * 5];
                float wv[5];
                #pragma unroll
                for (int q = 0; q < 5; ++q) wv[q] = wr[q];
                #pragma unroll
                for (int kw = 0; kw < 5; ++kw) {
                    #pragma unroll
                    for (int j = 0; j < 6; ++j)
                        acc2[j] += im2[j + kw] * wv[kw];
                }
            }
        }
        #pragma unroll
        for (int j = 0; j < 6; ++j) {
            acc2[j] += __shfl_xor(acc2[j], 1);
            acc2[j] += __shfl_xor(acc2[j], 2);
        }
        const float bias = b2[o];
        float hp[3];
        #pragma unroll
        for (int q = 0; q < 3; ++q) hp[q] = fmaxf(acc2[2 * q], acc2[2 * q + 1]);
        #pragma unroll
        for (int q = 0; q < 3; ++q) {
            float v = __shfl_xor(hp[q], 4);   // partner i^1 = lane^4
            hp[q] = fmaxf(hp[q], v);
        }
        if (cg == 0 && (i & 1) == 0) {
            #pragma unroll
            for (int q = 0; q < 3; ++q)
                s_h2[o * 9 + (i >> 1) * 3 + q] = fmaxf(hp[q] + bias, 0.0f);
        }
    }
    __syncthreads();

    // ---- Stage F: fc1 (90->32) + relu; 256 threads = 32 outputs x 8 lanes
    {
        const int of = t >> 3, l = t & 7;
        float acc = 0.0f;
        const float* wr = &fc1w[of * 90];
        #pragma unroll
        for (int m = 0; m < 12; ++m) {
            int j = l + 8 * m;
            if (j < 90) acc += s_h2[j] * wr[j];
        }
        acc += __shfl_xor(acc, 1);
        acc += __shfl_xor(acc, 2);
        acc += __shfl_xor(acc, 4);
        if (l == 0) s_fch[of] = fmaxf(acc + fc1b[of], 0.0f);
    }
    __syncthreads();

    // ---- Stage G: fc2 (32->6); 48 threads = 6 outputs x 8 lanes -> theta to ws
    if (t < 48) {
        const int of = t >> 3, l = t & 7;
        float acc = 0.0f;
        const float* wr = &fc2w[of * 32];
        #pragma unroll
        for (int m = 0; m < 4; ++m) {
            int j = l + 8 * m;
            acc += s_fch[j] * wr[j];
        }
        acc += __shfl_xor(acc, 1);
        acc += __shfl_xor(acc, 2);
        acc += __shfl_xor(acc, 4);
        if (l == 0) theta_ws[(size_t)n * 6 + of] = acc + fc2b[of];
    }
}

__launch_bounds__(256)
__global__ void stn_sample_kernel(
    const float* __restrict__ x,
    const float* __restrict__ theta_ws,
    float* __restrict__ out)
{
    const int t = threadIdx.x;
    const int n = blockIdx.x;
    const float* tw = theta_ws + (size_t)n * 6;
    const float t00 = tw[0], t01 = tw[1], t02 = tw[2];
    const float t10 = tw[3], t11 = tw[4], t12 = tw[5];
    const float* img = x + (size_t)n * 2352;       // HWC
    float* outp = out + (size_t)n * 2352;

    for (int p = t; p < 784; p += 256) {
        int h = p / 28, w = p - 28 * h;
        float xs = (2.0f * w + 1.0f) * (1.0f / 28.0f) - 1.0f;
        float ys = (2.0f * h + 1.0f) * (1.0f / 28.0f) - 1.0f;
        float gx = t00 * xs + t01 * ys + t02;
        float gy = t10 * xs + t11 * ys + t12;
        float ix = ((gx + 1.0f) * 28.0f - 1.0f) * 0.5f;
        float iy = ((gy + 1.0f) * 28.0f - 1.0f) * 0.5f;
        float x0f = floorf(ix), y0f = floorf(iy);
        float wx1 = ix - x0f, wx0 = 1.0f - wx1;
        float wy1 = iy - y0f, wy0 = 1.0f - wy1;
        int x0 = (int)x0f, y0 = (int)y0f;
        int x1 = x0 + 1, y1 = y0 + 1;
        float fx0 = (x0 >= 0 && x0 < 28) ? 1.0f : 0.0f;
        float fx1 = (x1 >= 0 && x1 < 28) ? 1.0f : 0.0f;
        float fy0 = (y0 >= 0 && y0 < 28) ? 1.0f : 0.0f;
        float fy1 = (y1 >= 0 && y1 < 28) ? 1.0f : 0.0f;
        float w00 = wx0 * wy0 * fx0 * fy0;
        float w10 = wx1 * wy0 * fx1 * fy0;
        float w01 = wx0 * wy1 * fx0 * fy1;
        float w11 = wx1 * wy1 * fx1 * fy1;
        int cx0 = min(max(x0, 0), 27), cx1 = min(max(x1, 0), 27);
        int cy0 = min(max(y0, 0), 27), cy1 = min(max(y1, 0), 27);
        const float* p00 = img + (cy0 * 28 + cx0) * 3;
        const float* p10 = img + (cy0 * 28 + cx1) * 3;
        const float* p01 = img + (cy1 * 28 + cx0) * 3;
        const float* p11 = img + (cy1 * 28 + cx1) * 3;
        float* o3 = outp + 3 * p;
        #pragma unroll
        for (int c = 0; c < 3; ++c) {
            o3[c] = p00[c] * w00 + p10[c] * w10 + p01[c] * w01 + p11[c] * w11;
        }
    }
}

extern "C" void kernel_launch(void* const* d_in, const int* in_sizes, int n_in,
                              void* d_out, int out_size, void* d_ws, size_t ws_size,
                              hipStream_t stream) {
    const float* x     = (const float*)d_in[0];
    const float* w1    = (const float*)d_in[1];
    const float* b1    = (const float*)d_in[2];
    const float* w2    = (const float*)d_in[3];
    const float* b2    = (const float*)d_in[4];
    const float* fc1w  = (const float*)d_in[5];
    const float* fc1b  = (const float*)d_in[6];
    const float* fc2w  = (const float*)d_in[7];
    const float* fc2b  = (const float*)d_in[8];
    float* outp  = (float*)d_out;
    float* theta = (float*)d_ws;   // 16384*6 floats = 393 KB

    const int n_img = 64 * 256;  // b*n
    stn_loc_kernel<<<dim3(n_img), dim3(256), 0, stream>>>(
        x, w1, b1, w2, b2, fc1w, fc1b, fc2w, fc2b, theta);
    stn_sample_kernel<<<dim3(n_img), dim3(256), 0, stream>>>(x, theta, outp);
}